// Round 6
// baseline (78.343 us; speedup 1.0000x reference)
//
#include <hip/hip_runtime.h>

// AdditiveSelfAttentionLayer: B=4, N=1024, D=64, fp32
// out[b,i,d] = sum_j softmax_j( sum_d' tanh(x[b,i,d']+x[b,j,d']) ) * x[b,j,d]
//
// Identities:
//   tanh(s) = 1 - 2/(1+e^{2s});  e_j = sum_d tanh = 64 - 2*rsum
//   e^{2s} = E_i[d]*E_j[d],  E = exp2(C*x), C = 2*log2(e)   (precomputed once)
//   PAIR MERGE (halves the rcp count — trans pipe is the limiter):
//     1/(1+a) + 1/(1+b) = (2+p)/(1+p+q),  p=a+b, q=ab
//   softmax shift 32: w_j = exp(e_j - 32) = exp2(32*log2e - C*rsum_j)
//
// Round 6: round-5 pk math re-expressed in NATIVE float2 vector ops
// (no inline asm — compiler emits v_pk_*_f32 itself and owns alignment).

#define NB 4
#define NN 1024
#define ND 64
#define TJ 64             // j-rows per LDS tile (lane = local j in tanh phase)
#define TI 8              // i-rows per WG
#define IPW 2             // i-rows per wave
#define NTILES (NN / TJ)  // 16

#if __has_builtin(__builtin_amdgcn_exp2f)
#define EXP2F(x) __builtin_amdgcn_exp2f(x)
#else
#define EXP2F(x) exp2f(x)
#endif
#if __has_builtin(__builtin_amdgcn_rcpf)
#define RCPF(x) __builtin_amdgcn_rcpf(x)
#else
#define RCPF(x) (1.0f / (x))
#endif

static constexpr float C_SCALE = 2.8853900817779268f;   // 2*log2(e)
static constexpr float K_SHIFT = 46.166241308446828f;   // 32*log2(e)

typedef float v2f __attribute__((ext_vector_type(2)));

#define PKFMA(a, b, c) __builtin_elementwise_fma((a), (b), (c))

__device__ __forceinline__ v2f vlo(float4 v) { v2f r; r.x = v.x; r.y = v.y; return r; }
__device__ __forceinline__ v2f vhi(float4 v) { v2f r; r.x = v.z; r.y = v.w; return r; }

// prep: E[i] = exp2(C * x[i]) for all B*N*D elements
__global__ __launch_bounds__(256) void prep_kernel(const float* __restrict__ x,
                                                   float* __restrict__ E) {
    int idx = blockIdx.x * 256 + threadIdx.x;
    float4 v = ((const float4*)x)[idx];
    float4 e;
    e.x = EXP2F(C_SCALE * v.x);
    e.y = EXP2F(C_SCALE * v.y);
    e.z = EXP2F(C_SCALE * v.z);
    e.w = EXP2F(C_SCALE * v.w);
    ((float4*)E)[idx] = e;
}

template <bool HAS_E>
__global__ __launch_bounds__(256) void addattn_kernel(const float* __restrict__ x,
                                                      const float* __restrict__ E,
                                                      float* __restrict__ out) {
    __shared__ float E_lds[TJ * ND];        // 16 KB, XOR-swizzled at float4 grain
    __shared__ float x_lds[TJ * ND];        // 16 KB, linear (PV reads coalesced)
    __shared__ float Ei_lds[TI * ND];       // 2 KB
    __shared__ float w_lds[4 * IPW * ND];   // 2 KB, per-wave private rows

    const int tid   = threadIdx.x;
    const int lane  = tid & 63;
    const int wave  = tid >> 6;
    const int wg    = blockIdx.x;
    const int b     = wg >> 7;              // 128 WGs per batch
    const int ibase = (wg & 127) * TI;

    const float* xb = x + (size_t)b * NN * ND;
    const float* Eb = E + (size_t)b * NN * ND;

    // stage E for this WG's TI i-rows (contiguous TI*ND floats)
    if (tid < TI * ND / 4) {
        if (HAS_E) {
            ((float4*)Ei_lds)[tid] = ((const float4*)(Eb + (size_t)ibase * ND))[tid];
        } else {
            float4 v = ((const float4*)(xb + (size_t)ibase * ND))[tid];
            float4 e;
            e.x = EXP2F(C_SCALE * v.x);
            e.y = EXP2F(C_SCALE * v.y);
            e.z = EXP2F(C_SCALE * v.z);
            e.w = EXP2F(C_SCALE * v.w);
            ((float4*)Ei_lds)[tid] = e;
        }
    }

    v2f acc0a = {0.f, 0.f}, acc0b = {0.f, 0.f};   // i0 numerator, packed over j-parity
    v2f acc1a = {0.f, 0.f}, acc1b = {0.f, 0.f};   // i1
    float dn0 = 0.f, dn1 = 0.f;                   // per-lane denom partials

    for (int t = 0; t < NTILES; ++t) {
        __syncthreads();   // protect LDS from previous tile's readers (publishes Ei at t=0)
        {
            const float4* srcx = (const float4*)(xb + (size_t)t * TJ * ND);
            const float4* srcE = (const float4*)(Eb + (size_t)t * TJ * ND);
            #pragma unroll
            for (int it = 0; it < (TJ * ND / 4) / 256; ++it) {   // 4 iters
                int idx = it * 256 + tid;
                int j   = idx >> 4;         // 16 float4 per row
                int c   = idx & 15;
                float4 xv = srcx[idx];
                ((float4*)x_lds)[idx] = xv;              // linear
                float4 ev;
                if (HAS_E) {
                    ev = srcE[idx];
                } else {
                    ev.x = EXP2F(C_SCALE * xv.x);
                    ev.y = EXP2F(C_SCALE * xv.y);
                    ev.z = EXP2F(C_SCALE * xv.z);
                    ev.w = EXP2F(C_SCALE * xv.w);
                }
                *(float4*)&E_lds[j * ND + ((c ^ (j & 15)) << 2)] = ev;  // swizzled
            }
        }
        __syncthreads();

        // ---- tanh phase: lane = local j; 2 i-rows per wave; pair-merged rcp ----
        // Per float4 chunk of d: a=(Ei*Ej).lo pair, b=(Ei*Ej).hi pair;
        // 1/(1+a)+1/(1+b) = (2+p)/(1+p+q) — 2 rcp per 4 d-elements.
        const int xorkey = lane & 15;
        const float* Ei0 = &Ei_lds[(wave * IPW + 0) * ND];
        const float* Ei1 = &Ei_lds[(wave * IPW + 1) * ND];
        v2f rs0e = {0.f, 0.f}, rs0o = {0.f, 0.f};   // 2 packed chains per i-row
        v2f rs1e = {0.f, 0.f}, rs1o = {0.f, 0.f};
        #pragma unroll
        for (int c = 0; c < 16; ++c) {
            float4 ejq = *(const float4*)&E_lds[lane * ND + ((c ^ xorkey) << 2)];
            v2f ej_lo = vlo(ejq), ej_hi = vhi(ejq);
            {
                float4 eiq = *(const float4*)&Ei0[c * 4];   // same-addr broadcast
                v2f a = vlo(eiq) * ej_lo;
                v2f q = vhi(eiq) * ej_hi;
                v2f p = a + q;
                v2f r = PKFMA(a, q, p + 1.0f);              // 1 + p + ab
                v2f tt; tt.x = RCPF(r.x); tt.y = RCPF(r.y);
                if (c & 1) rs0o = PKFMA(p + 2.0f, tt, rs0o);
                else       rs0e = PKFMA(p + 2.0f, tt, rs0e);
            }
            {
                float4 eiq = *(const float4*)&Ei1[c * 4];
                v2f a = vlo(eiq) * ej_lo;
                v2f q = vhi(eiq) * ej_hi;
                v2f p = a + q;
                v2f r = PKFMA(a, q, p + 1.0f);
                v2f tt; tt.x = RCPF(r.x); tt.y = RCPF(r.y);
                if (c & 1) rs1o = PKFMA(p + 2.0f, tt, rs1o);
                else       rs1e = PKFMA(p + 2.0f, tt, rs1e);
            }
        }
        v2f rs0 = rs0e + rs0o;
        v2f rs1 = rs1e + rs1o;
        float r0 = rs0.x + rs0.y;
        float r1 = rs1.x + rs1.y;
        float w0 = EXP2F(fmaf(-C_SCALE, r0, K_SHIFT));  // = exp(e_j - 32)
        float w1 = EXP2F(fmaf(-C_SCALE, r1, K_SHIFT));
        dn0 += w0;
        dn1 += w1;

        // publish w to this wave's private LDS rows (same-wave round trip; no barrier)
        w_lds[(wave * IPW + 0) * ND + lane] = w0;
        w_lds[(wave * IPW + 1) * ND + lane] = w1;

        // ---- PV phase: acc[i, d=lane] += sum_j w_ij * x[j][lane] ----
        // x pairs 256 B apart -> compiler merges to ds_read2_b32; packed fma.
        #pragma unroll
        for (int jq = 0; jq < 16; ++jq) {
            float4 w0q = *(const float4*)&w_lds[(wave * IPW + 0) * ND + jq * 4]; // broadcast
            float4 w1q = *(const float4*)&w_lds[(wave * IPW + 1) * ND + jq * 4];
            const int j0 = jq * 4;
            v2f xv01, xv23;
            xv01.x = x_lds[(j0 + 0) * ND + lane];
            xv01.y = x_lds[(j0 + 1) * ND + lane];
            xv23.x = x_lds[(j0 + 2) * ND + lane];
            xv23.y = x_lds[(j0 + 3) * ND + lane];
            acc0a = PKFMA(vlo(w0q), xv01, acc0a);
            acc0b = PKFMA(vhi(w0q), xv23, acc0b);
            acc1a = PKFMA(vlo(w1q), xv01, acc1a);
            acc1b = PKFMA(vhi(w1q), xv23, acc1b);
        }
    }

    // reduce denominators across lanes (each lane held w for its j's)
    #pragma unroll
    for (int s = 0; s < 6; ++s) {
        dn0 += __shfl_xor(dn0, 1 << s, 64);
        dn1 += __shfl_xor(dn1, 1 << s, 64);
    }

    const float num0 = (acc0a.x + acc0a.y) + (acc0b.x + acc0b.y);
    const float num1 = (acc1a.x + acc1a.y) + (acc1b.x + acc1b.y);
    const int i0 = ibase + wave * IPW;
    out[((size_t)b * NN + i0) * ND + lane]     = num0 * RCPF(dn0);
    out[((size_t)b * NN + i0 + 1) * ND + lane] = num1 * RCPF(dn1);
}

extern "C" void kernel_launch(void* const* d_in, const int* in_sizes, int n_in,
                              void* d_out, int out_size, void* d_ws, size_t ws_size,
                              hipStream_t stream) {
    const float* x = (const float*)d_in[0];
    float* out = (float*)d_out;
    const size_t e_bytes = (size_t)NB * NN * ND * sizeof(float);   // 1 MB

    dim3 grid(NB * (NN / TI));   // 512 workgroups
    dim3 block(256);

    if (ws_size >= e_bytes) {
        float* E = (float*)d_ws;
        prep_kernel<<<dim3(NB * NN * ND / 4 / 256), dim3(256), 0, stream>>>(x, E);
        addattn_kernel<true><<<grid, block, 0, stream>>>(x, E, out);
    } else {
        addattn_kernel<false><<<grid, block, 0, stream>>>(x, (const float*)nullptr, out);
    }
}

// Round 7
// 65.244 us; speedup vs baseline: 1.2008x; 1.2008x over previous
//
#include <hip/hip_runtime.h>

// AdditiveSelfAttentionLayer: B=4, N=1024, D=64, fp32
// out[b,i,d] = sum_j softmax_j( sum_d' tanh(x[b,i,d']+x[b,j,d']) ) * x[b,j,d]
//
// Identities:
//   tanh(s) = 1 - 2/(1+e^{2s});  e_j = sum_d tanh = 64 - 2*rsum
//   e^{2s} = E_i[d]*E_j[d],  E = exp2(C*x), C = 2*log2(e)   (precomputed once)
//   PAIR MERGE: 1/(1+a) + 1/(1+b) = (2+p)/(1+p+q),  p=a+b, q=ab  (native v2f pk ops)
//   softmax shift 32: w_j = exp(e_j - 32) = exp2(32*log2e - C*rsum_j)
//
// Round 7: kill ALL broadcast LDS traffic (round-6 post-mortem: stall-bound on
// LDS, not trans). lane=j; out-row accumulated IN REGISTERS (end butterfly,
// round-1-verified); Ei via wave-uniform scalar loads; w stays in-lane.
// LDS per wave-tile: 96KB -> 32KB. TI=4 -> 1024 WGs -> 3-4 WG/CU.

#define NB 4
#define NN 1024
#define ND 64
#define TJ 64             // j-rows per LDS tile (lane = local j)
#define TI 4              // i-rows per WG = waves per WG (IPW=1)
#define NTILES (NN / TJ)  // 16

#if __has_builtin(__builtin_amdgcn_exp2f)
#define EXP2F(x) __builtin_amdgcn_exp2f(x)
#else
#define EXP2F(x) exp2f(x)
#endif
#if __has_builtin(__builtin_amdgcn_rcpf)
#define RCPF(x) __builtin_amdgcn_rcpf(x)
#else
#define RCPF(x) (1.0f / (x))
#endif

static constexpr float C_SCALE = 2.8853900817779268f;   // 2*log2(e)
static constexpr float K_SHIFT = 46.166241308446828f;   // 32*log2(e)

typedef float v2f __attribute__((ext_vector_type(2)));

#define PKFMA(a, b, c) __builtin_elementwise_fma((a), (b), (c))

__device__ __forceinline__ v2f vlo(float4 v) { v2f r; r.x = v.x; r.y = v.y; return r; }
__device__ __forceinline__ v2f vhi(float4 v) { v2f r; r.x = v.z; r.y = v.w; return r; }

// prep: E[i] = exp2(C * x[i]) for all B*N*D elements
__global__ __launch_bounds__(256) void prep_kernel(const float* __restrict__ x,
                                                   float* __restrict__ E) {
    int idx = blockIdx.x * 256 + threadIdx.x;
    float4 v = ((const float4*)x)[idx];
    float4 e;
    e.x = EXP2F(C_SCALE * v.x);
    e.y = EXP2F(C_SCALE * v.y);
    e.z = EXP2F(C_SCALE * v.z);
    e.w = EXP2F(C_SCALE * v.w);
    ((float4*)E)[idx] = e;
}

template <bool HAS_E>
__global__ __launch_bounds__(256, 3) void addattn_kernel(const float* __restrict__ x,
                                                         const float* __restrict__ E,
                                                         float* __restrict__ out) {
    __shared__ float E_lds[TJ * ND];   // 16 KB, XOR-swizzled at float4 grain
    __shared__ float x_lds[TJ * ND];   // 16 KB, same swizzle (row reads now)

    const int tid   = threadIdx.x;
    const int lane  = tid & 63;
    const int wave  = tid >> 6;
    const int wg    = blockIdx.x;
    const int b     = wg >> 8;                       // 256 WGs per batch
    const int ibase = (wg & 255) * TI;
    // wave-uniform i-row index (forced into SGPR so Ei loads become s_loads)
    const int i0    = __builtin_amdgcn_readfirstlane(ibase + wave);

    const float* xb  = x + (size_t)b * NN * ND;
    const float* Eb  = E + (size_t)b * NN * ND;
    const float* Eip = Eb + (size_t)i0 * ND;         // uniform pointer

    // fallback (no workspace): Ei in VGPRs, computed once
    v2f ei2[32];
    if (!HAS_E) {
        #pragma unroll
        for (int c = 0; c < 16; ++c) {
            float4 xiq = *(const float4*)&xb[(size_t)i0 * ND + c * 4];  // uniform
            v2f lo, hi;
            lo.x = EXP2F(C_SCALE * xiq.x);
            lo.y = EXP2F(C_SCALE * xiq.y);
            hi.x = EXP2F(C_SCALE * xiq.z);
            hi.y = EXP2F(C_SCALE * xiq.w);
            ei2[2 * c] = lo;
            ei2[2 * c + 1] = hi;
        }
    }

    v2f acc2[32];                       // out[i0] numerator, d-pairs, in-lane
    #pragma unroll
    for (int k = 0; k < 32; ++k) acc2[k] = (v2f){0.f, 0.f};
    float dn = 0.f;                     // per-lane denominator partial

    for (int t = 0; t < NTILES; ++t) {
        __syncthreads();   // protect LDS from previous tile's readers
        {
            const float4* srcx = (const float4*)(xb + (size_t)t * TJ * ND);
            const float4* srcE = (const float4*)(Eb + (size_t)t * TJ * ND);
            #pragma unroll
            for (int it = 0; it < (TJ * ND / 4) / 256; ++it) {   // 4 iters
                int idx = it * 256 + tid;
                int j   = idx >> 4;         // 16 float4 per row
                int c   = idx & 15;
                int w   = j * ND + ((c ^ (j & 15)) << 2);        // slot c^(j&15) holds chunk c
                float4 xv = srcx[idx];
                *(float4*)&x_lds[w] = xv;
                float4 ev;
                if (HAS_E) {
                    ev = srcE[idx];
                } else {
                    ev.x = EXP2F(C_SCALE * xv.x);
                    ev.y = EXP2F(C_SCALE * xv.y);
                    ev.z = EXP2F(C_SCALE * xv.z);
                    ev.w = EXP2F(C_SCALE * xv.w);
                }
                *(float4*)&E_lds[w] = ev;
            }
        }
        __syncthreads();

        // ---- tanh phase: lane = local j; pair-merged packed rcp ----
        const int key = lane & 15;
        v2f rse = {0.f, 0.f}, rso = {0.f, 0.f};
        #pragma unroll
        for (int c = 0; c < 16; ++c) {
            // slot (c^key) holds d-chunk c for row j=lane
            float4 ejq = *(const float4*)&E_lds[lane * ND + ((c ^ key) << 2)];
            v2f eil, eih;
            if (HAS_E) {
                float4 eiq = *(const float4*)&Eip[c * 4];   // scalar (SGPR) load
                eil = vlo(eiq); eih = vhi(eiq);
            } else {
                eil = ei2[2 * c]; eih = ei2[2 * c + 1];
            }
            v2f a = eil * vlo(ejq);
            v2f q = eih * vhi(ejq);
            v2f p = a + q;
            v2f r = PKFMA(a, q, p + 1.0f);              // 1 + p + ab
            v2f tt; tt.x = RCPF(r.x); tt.y = RCPF(r.y);
            if (c & 1) rso = PKFMA(p + 2.0f, tt, rso);
            else       rse = PKFMA(p + 2.0f, tt, rse);
        }
        v2f rs = rse + rso;
        float rsum = rs.x + rs.y;
        float w = EXP2F(fmaf(-C_SCALE, rsum, K_SHIFT)); // = exp(e_j - 32)
        dn += w;
        v2f w2; w2.x = w; w2.y = w;

        // ---- PV phase (in-register): acc[d] += w * x[j=lane][d] ----
        #pragma unroll
        for (int c = 0; c < 16; ++c) {
            float4 xq = *(const float4*)&x_lds[lane * ND + ((c ^ key) << 2)];
            acc2[2 * c]     = PKFMA(w2, vlo(xq), acc2[2 * c]);
            acc2[2 * c + 1] = PKFMA(w2, vhi(xq), acc2[2 * c + 1]);
        }
    }

    // ---- cross-lane transpose-reduction (round-1-verified butterfly) ----
    // After 6 halving steps, accf[0] on lane l = sum over lanes of accf[d=l].
    float* accf = (float*)acc2;
    #pragma unroll
    for (int s = 0; s < 6; ++s) {
        const int half = 32 >> s;
        const int sel  = (lane >> (5 - s)) & 1;
        #pragma unroll
        for (int k = 0; k < half; ++k) {
            float keep = sel ? accf[k + half] : accf[k];
            float send = sel ? accf[k] : accf[k + half];
            float recv = __shfl_xor(send, half, 64);
            accf[k] = keep + recv;
        }
    }
    #pragma unroll
    for (int s = 0; s < 6; ++s) dn += __shfl_xor(dn, 1 << s, 64);

    out[((size_t)b * NN + i0) * ND + lane] = accf[0] * RCPF(dn);
}

extern "C" void kernel_launch(void* const* d_in, const int* in_sizes, int n_in,
                              void* d_out, int out_size, void* d_ws, size_t ws_size,
                              hipStream_t stream) {
    const float* x = (const float*)d_in[0];
    float* out = (float*)d_out;
    const size_t e_bytes = (size_t)NB * NN * ND * sizeof(float);   // 1 MB

    dim3 grid(NB * (NN / TI));   // 1024 workgroups
    dim3 block(256);

    if (ws_size >= e_bytes) {
        float* E = (float*)d_ws;
        prep_kernel<<<dim3(NB * NN * ND / 4 / 256), dim3(256), 0, stream>>>(x, E);
        addattn_kernel<true><<<grid, block, 0, stream>>>(x, E, out);
    } else {
        addattn_kernel<false><<<grid, block, 0, stream>>>(x, (const float*)nullptr, out);
    }
}